// Round 1
// baseline (427.440 us; speedup 1.0000x reference)
//
#include <hip/hip_runtime.h>
#include <hip/hip_bf16.h>

// GCN: 2x (GCNConv -> ReLU -> BatchNorm) -> Linear
// B=2, N=20000, E=640000, H=IN=128, OUT=10
//
// Round-4 structure (8 dispatches):
//  - ELL adjacency in ONE scatter pass (atomic cursor == degree counter)
//  - h pre-scaled by dinv at GEMM epilogue: agg is a pure unweighted sum
//    (norm = dinv[s]*dinv[d]  =>  out = dinv[d] * sum(dinv[s]*h[s]))
//  - agg: 64 lanes/node (uint2/lane, no intra-wave divergence), 8/4/1-wide
//    software-pipelined gathers, fused self-loop+bias+ReLU
//  - BN stats FUSED into agg epilogue (shfl+LDS reduce -> 256 atomicAdds/blk)
//  - BN affine computed per-block in consumers (gemm2: a,c + d=c@W2 init;
//    gemmout: a,c in-register) -- no single-workgroup finalize kernels
//  - 12 -> 8 dispatches

constexpr int Nn   = 20000;
constexpr int Ee   = 640000;
constexpr int OUTd = 10;
constexpr int Mm   = 2 * Nn;   // 40000 rows
constexpr int ELLW = 96;       // max degree slots; Poisson(32) => P(overflow) ~ 1e-14
#define EPSV 1e-5f
constexpr float INV_M = 1.0f / (float)Mm;

using frag16 = __attribute__((ext_vector_type(8))) short;  // 8 bf16
using f32x4  = __attribute__((ext_vector_type(4))) float;

__device__ inline short bf(float f) {
    union { __hip_bfloat16 h; short s; } u;
    u.h = __float2bfloat16(f);
    return u.s;
}
__device__ inline float lo16(unsigned u) { union { unsigned v; float f; } x; x.v = u << 16;        return x.f; }
__device__ inline float hi16(unsigned u) { union { unsigned v; float f; } x; x.v = u & 0xffff0000u; return x.f; }
__device__ inline unsigned pack2(float f0, float f1) {
    return (unsigned)(unsigned short)bf(f0) | ((unsigned)(unsigned short)bf(f1) << 16);
}

// ---------------- adjacency: one-pass ELL scatter ----------------
__global__ __launch_bounds__(256) void scatter_ell_k(const int* __restrict__ src, const int* __restrict__ dst,
                                                     int* __restrict__ cnt, int* __restrict__ ell) {
    int e = blockIdx.x * 256 + threadIdx.x;
    if (e < Ee) {
        int d = dst[e];
        int pos = atomicAdd(&cnt[d], 1);
        if (pos < ELLW) ell[(size_t)d * ELLW + pos] = src[e];
    }
}

__global__ __launch_bounds__(256) void dinv_k(const int* __restrict__ cnt, float* __restrict__ dinv) {
    int n = blockIdx.x * 256 + threadIdx.x;
    if (n < Nn) dinv[n] = rsqrtf((float)cnt[n] + 1.0f);  // +1 self-loop
}

// ---------------- GEMM1: (40000 x 128 fp32) @ (128 x 128) -> dinv-scaled bf16 interleaved ----------------
// Block: 256 thr = 4 waves, 64 rows. Output Hout[(n*2+b)*128 + col] = dinv[n] * (x@W1), row rg = b*Nn+n.
__global__ __launch_bounds__(256) void gemm1_k(const float* __restrict__ A,
                                               const float* __restrict__ W,
                                               const float* __restrict__ dinv,
                                               unsigned short* __restrict__ Hout) {
    __shared__ short Wl[128 * 136];  // Wl[n*136 + k] bf16; stride 272B -> free 2-way
    int t = threadIdx.x;

    for (int it = 0; it < 8; ++it) {
        int lin = it * 256 + t;
        int kp  = lin & 63;
        int n4  = (lin >> 6) * 4;
        float4 w0 = *(const float4*)(W + (size_t)(2 * kp) * 128 + n4);
        float4 w1 = *(const float4*)(W + (size_t)(2 * kp + 1) * 128 + n4);
        *(unsigned*)&Wl[(n4 + 0) * 136 + 2 * kp] = pack2(w0.x, w1.x);
        *(unsigned*)&Wl[(n4 + 1) * 136 + 2 * kp] = pack2(w0.y, w1.y);
        *(unsigned*)&Wl[(n4 + 2) * 136 + 2 * kp] = pack2(w0.z, w1.z);
        *(unsigned*)&Wl[(n4 + 3) * 136 + 2 * kp] = pack2(w0.w, w1.w);
    }
    __syncthreads();

    int wv = t >> 6, l = t & 63;
    int row_q = l >> 4, lane16 = l & 15;
    int row0 = blockIdx.x * 64 + wv * 16;

    frag16 a[4];
    const float* Arow = A + (size_t)(row0 + lane16) * 128;
    #pragma unroll
    for (int q = 0; q < 4; ++q) {
        int k0 = q * 32 + row_q * 8;
        float4 v0 = *(const float4*)(Arow + k0);
        float4 v1 = *(const float4*)(Arow + k0 + 4);
        frag16 fa = { bf(v0.x), bf(v0.y), bf(v0.z), bf(v0.w),
                      bf(v1.x), bf(v1.y), bf(v1.z), bf(v1.w) };
        a[q] = fa;
    }

    f32x4 acc[8];
    #pragma unroll
    for (int c = 0; c < 8; ++c) acc[c] = (f32x4){0.f, 0.f, 0.f, 0.f};

    #pragma unroll
    for (int c = 0; c < 8; ++c) {
        int n = c * 16 + lane16;
        #pragma unroll
        for (int q = 0; q < 4; ++q) {
            int k0 = q * 32 + row_q * 8;
            frag16 b = *(const frag16*)&Wl[n * 136 + k0];
            acc[c] = __builtin_amdgcn_mfma_f32_16x16x32_bf16(a[q], b, acc[c], 0, 0, 0);
        }
    }

    #pragma unroll
    for (int r = 0; r < 4; ++r) {
        int rg = row0 + row_q * 4 + r;
        int b  = rg >= Nn;
        int n  = rg - b * Nn;
        float dv = dinv[n];
        unsigned short* dst = Hout + (size_t)n * 256 + b * 128;
        #pragma unroll
        for (int c = 0; c < 8; ++c)
            dst[c * 16 + lane16] = (unsigned short)bf(acc[c][r] * dv);
    }
}

// ---------------- GEMM2: (bf16 act) @ (diag(a1)*W2) + c1@W2 -> dinv-scaled bf16 ----------------
// BN1 affine (a,c) computed per-block from global stat sums S (atomic-free read);
// d = c@W2 computed per-block as acc init. No finalize dispatch.
__global__ __launch_bounds__(256) void gemm2_k(const unsigned short* __restrict__ Abf,
                                               const float* __restrict__ W,
                                               const float* __restrict__ g,
                                               const float* __restrict__ bt,
                                               const float* __restrict__ S,
                                               const float* __restrict__ dinv,
                                               unsigned short* __restrict__ Hout) {
    __shared__ short Wl[128 * 136];
    __shared__ float al[128], cl[128], dpart[2][128];
    int t = threadIdx.x;

    if (t < 128) {
        float s  = S[t];
        float ss = S[128 + t];
        float m   = s * INV_M;
        float var = ss * INV_M - m * m;
        float a   = g[t] * rsqrtf(var + EPSV);
        float c   = bt[t] - m * a;
        al[t] = a; cl[t] = c;
    }
    __syncthreads();

    // stage W scaled by a (rows k scaled by a[k])
    for (int it = 0; it < 8; ++it) {
        int lin = it * 256 + t;
        int kp  = lin & 63;
        int n4  = (lin >> 6) * 4;
        float a0 = al[2 * kp], a1 = al[2 * kp + 1];
        float4 w0 = *(const float4*)(W + (size_t)(2 * kp) * 128 + n4);
        float4 w1 = *(const float4*)(W + (size_t)(2 * kp + 1) * 128 + n4);
        w0.x *= a0; w0.y *= a0; w0.z *= a0; w0.w *= a0;
        w1.x *= a1; w1.y *= a1; w1.z *= a1; w1.w *= a1;
        *(unsigned*)&Wl[(n4 + 0) * 136 + 2 * kp] = pack2(w0.x, w1.x);
        *(unsigned*)&Wl[(n4 + 1) * 136 + 2 * kp] = pack2(w0.y, w1.y);
        *(unsigned*)&Wl[(n4 + 2) * 136 + 2 * kp] = pack2(w0.z, w1.z);
        *(unsigned*)&Wl[(n4 + 3) * 136 + 2 * kp] = pack2(w0.w, w1.w);
    }

    // d[col] = sum_k c[k] * W[k][col], split over two half-K per thread
    {
        int col = t & 127, hh = t >> 7;
        const float* Wc0 = W + (size_t)(hh * 64) * 128 + col;
        float dp = 0.f;
        #pragma unroll 8
        for (int k = 0; k < 64; ++k) dp += cl[hh * 64 + k] * Wc0[(size_t)k * 128];
        dpart[hh][col] = dp;
    }
    __syncthreads();

    int wv = t >> 6, l = t & 63;
    int row_q = l >> 4, lane16 = l & 15;
    int row0 = blockIdx.x * 64 + wv * 16;

    int rgA = row0 + lane16;
    int bA  = rgA >= Nn;
    int nA  = rgA - bA * Nn;
    const unsigned short* Arow = Abf + (size_t)nA * 256 + bA * 128;
    frag16 a[4];
    #pragma unroll
    for (int q = 0; q < 4; ++q) {
        int k0 = q * 32 + row_q * 8;
        a[q] = *(const frag16*)(Arow + k0);
    }

    f32x4 acc[8];
    #pragma unroll
    for (int c = 0; c < 8; ++c) {
        int n = c * 16 + lane16;
        float d = dpart[0][n] + dpart[1][n];
        acc[c] = (f32x4){d, d, d, d};
    }

    #pragma unroll
    for (int c = 0; c < 8; ++c) {
        int n = c * 16 + lane16;
        #pragma unroll
        for (int q = 0; q < 4; ++q) {
            int k0 = q * 32 + row_q * 8;
            frag16 b = *(const frag16*)&Wl[n * 136 + k0];
            acc[c] = __builtin_amdgcn_mfma_f32_16x16x32_bf16(a[q], b, acc[c], 0, 0, 0);
        }
    }

    #pragma unroll
    for (int r = 0; r < 4; ++r) {
        int rg = row0 + row_q * 4 + r;
        int b  = rg >= Nn;
        int n  = rg - b * Nn;
        float dv = dinv[n];
        unsigned short* dst = Hout + (size_t)n * 256 + b * 128;
        #pragma unroll
        for (int c = 0; c < 8; ++c)
            dst[c * 16 + lane16] = (unsigned short)bf(acc[c][r] * dv);
    }
}

// ---------------- Aggregation: pure-sum gather over pre-scaled bf16 h + fused BN stats ----------------
// Block: 256 thr = 4 waves = 4 nodes, 64 lanes/node (no intra-wave divergence).
// Lane l: batch l>>5, cols (l&31)*4..+3 (one 8B uint2 load/edge -> 512B/edge/wave).
__global__ __launch_bounds__(256) void agg_k(const unsigned short* __restrict__ h,
                                             const int* __restrict__ ell,
                                             const int* __restrict__ cnt,
                                             const float* __restrict__ dinv,
                                             const float* __restrict__ bias,
                                             unsigned short* __restrict__ act,
                                             float* __restrict__ S) {
    int t = threadIdx.x;
    int wv = t >> 6;
    int l  = t & 63;
    int n  = __builtin_amdgcn_readfirstlane(blockIdx.x * 4 + wv);  // wave-uniform -> SGPR
    int b  = l >> 5;
    int g  = l & 31;
    int off = b * 32 + g;  // uint2 offset within a 64-uint2 row

    const uint2* h2 = (const uint2*)h;

    // self-loop (h already dinv-scaled)
    uint2 u = h2[(size_t)n * 64 + off];
    float a0 = lo16(u.x), a1 = hi16(u.x), a2 = lo16(u.y), a3 = hi16(u.y);

    int deg = cnt[n]; if (deg > ELLW) deg = ELLW;
    const int* row = ell + (size_t)n * ELLW;

    int j = 0;
    for (; j + 7 < deg; j += 8) {
        int s0 = row[j],   s1 = row[j+1], s2 = row[j+2], s3 = row[j+3];
        int s4 = row[j+4], s5 = row[j+5], s6 = row[j+6], s7 = row[j+7];
        uint2 v0 = h2[(size_t)s0 * 64 + off];
        uint2 v1 = h2[(size_t)s1 * 64 + off];
        uint2 v2 = h2[(size_t)s2 * 64 + off];
        uint2 v3 = h2[(size_t)s3 * 64 + off];
        uint2 v4 = h2[(size_t)s4 * 64 + off];
        uint2 v5 = h2[(size_t)s5 * 64 + off];
        uint2 v6 = h2[(size_t)s6 * 64 + off];
        uint2 v7 = h2[(size_t)s7 * 64 + off];
        a0 += lo16(v0.x); a1 += hi16(v0.x); a2 += lo16(v0.y); a3 += hi16(v0.y);
        a0 += lo16(v1.x); a1 += hi16(v1.x); a2 += lo16(v1.y); a3 += hi16(v1.y);
        a0 += lo16(v2.x); a1 += hi16(v2.x); a2 += lo16(v2.y); a3 += hi16(v2.y);
        a0 += lo16(v3.x); a1 += hi16(v3.x); a2 += lo16(v3.y); a3 += hi16(v3.y);
        a0 += lo16(v4.x); a1 += hi16(v4.x); a2 += lo16(v4.y); a3 += hi16(v4.y);
        a0 += lo16(v5.x); a1 += hi16(v5.x); a2 += lo16(v5.y); a3 += hi16(v5.y);
        a0 += lo16(v6.x); a1 += hi16(v6.x); a2 += lo16(v6.y); a3 += hi16(v6.y);
        a0 += lo16(v7.x); a1 += hi16(v7.x); a2 += lo16(v7.y); a3 += hi16(v7.y);
    }
    for (; j + 3 < deg; j += 4) {
        int s0 = row[j], s1 = row[j+1], s2 = row[j+2], s3 = row[j+3];
        uint2 v0 = h2[(size_t)s0 * 64 + off];
        uint2 v1 = h2[(size_t)s1 * 64 + off];
        uint2 v2 = h2[(size_t)s2 * 64 + off];
        uint2 v3 = h2[(size_t)s3 * 64 + off];
        a0 += lo16(v0.x); a1 += hi16(v0.x); a2 += lo16(v0.y); a3 += hi16(v0.y);
        a0 += lo16(v1.x); a1 += hi16(v1.x); a2 += lo16(v1.y); a3 += hi16(v1.y);
        a0 += lo16(v2.x); a1 += hi16(v2.x); a2 += lo16(v2.y); a3 += hi16(v2.y);
        a0 += lo16(v3.x); a1 += hi16(v3.x); a2 += lo16(v3.y); a3 += hi16(v3.y);
    }
    for (; j < deg; ++j) {
        int s0 = row[j];
        uint2 v0 = h2[(size_t)s0 * 64 + off];
        a0 += lo16(v0.x); a1 += hi16(v0.x); a2 += lo16(v0.y); a3 += hi16(v0.y);
    }

    float dn = dinv[n];
    int cb = g * 4;
    float4 bb = *(const float4*)(bias + cb);
    float o0 = fmaxf(fmaf(dn, a0, bb.x), 0.f);
    float o1 = fmaxf(fmaf(dn, a1, bb.y), 0.f);
    float o2 = fmaxf(fmaf(dn, a2, bb.z), 0.f);
    float o3 = fmaxf(fmaf(dn, a3, bb.w), 0.f);

    uint2 st;
    st.x = pack2(o0, o1); st.y = pack2(o2, o3);
    *(uint2*)(act + (size_t)n * 256 + b * 128 + cb) = st;

    // ---- fused BN stats: per-block col partials -> 256 global atomics ----
    float q0 = o0 * o0, q1 = o1 * o1, q2 = o2 * o2, q3 = o3 * o3;
    float s0 = o0 + __shfl_xor(o0, 32);   // reduce over batch pair
    float s1 = o1 + __shfl_xor(o1, 32);
    float s2 = o2 + __shfl_xor(o2, 32);
    float s3 = o3 + __shfl_xor(o3, 32);
    float t0 = q0 + __shfl_xor(q0, 32);
    float t1 = q1 + __shfl_xor(q1, 32);
    float t2 = q2 + __shfl_xor(q2, 32);
    float t3 = q3 + __shfl_xor(q3, 32);

    __shared__ float sh[4][32][9];  // pad 9 to spread banks
    if (l < 32) {
        float* p = sh[wv][l];
        p[0] = s0; p[1] = s1; p[2] = s2; p[3] = s3;
        p[4] = t0; p[5] = t1; p[6] = t2; p[7] = t3;
    }
    __syncthreads();
    int gg = t >> 3, slot = t & 7;
    float v = sh[0][gg][slot] + sh[1][gg][slot] + sh[2][gg][slot] + sh[3][gg][slot];
    atomicAdd(&S[(slot >= 4 ? 128 : 0) + gg * 4 + (slot & 3)], v);
}

// ---------------- classifier: (bf16 act, BN2 affine computed in-block) @ Wc + bc ----------------
__global__ __launch_bounds__(256) void gemmout_k(const unsigned short* __restrict__ act,
                                                 const float* __restrict__ Wc,
                                                 const float* __restrict__ bc,
                                                 const float* __restrict__ g,
                                                 const float* __restrict__ bt,
                                                 const float* __restrict__ S,
                                                 float* __restrict__ out) {
    __shared__ float Wl[128 * OUTd];
    __shared__ float bl[OUTd];
    __shared__ float al[128], cl[128];
    int t = threadIdx.x;
    for (int i = t; i < 128 * OUTd; i += 256) Wl[i] = Wc[i];
    if (t < OUTd) bl[t] = bc[t];
    if (t < 128) {
        float s  = S[t];
        float ss = S[128 + t];
        float m   = s * INV_M;
        float var = ss * INV_M - m * m;
        float a   = g[t] * rsqrtf(var + EPSV);
        al[t] = a;
        cl[t] = bt[t] - m * a;
    }
    __syncthreads();

    int r = blockIdx.x * 256 + t;
    if (r >= Mm) return;
    int b = r >= Nn;
    int n = r - b * Nn;

    float acc[OUTd];
    #pragma unroll
    for (int jj = 0; jj < OUTd; jj++) acc[jj] = 0.f;

    const uint4* a4 = (const uint4*)(act + (size_t)n * 256 + b * 128);
    #pragma unroll 4
    for (int k4 = 0; k4 < 16; k4++) {
        uint4 u = a4[k4];
        int k = k4 * 8;
        float e0 = lo16(u.x) * al[k+0] + cl[k+0];
        float e1 = hi16(u.x) * al[k+1] + cl[k+1];
        float e2 = lo16(u.y) * al[k+2] + cl[k+2];
        float e3 = hi16(u.y) * al[k+3] + cl[k+3];
        float e4 = lo16(u.z) * al[k+4] + cl[k+4];
        float e5 = hi16(u.z) * al[k+5] + cl[k+5];
        float e6 = lo16(u.w) * al[k+6] + cl[k+6];
        float e7 = hi16(u.w) * al[k+7] + cl[k+7];
        #pragma unroll
        for (int jj = 0; jj < OUTd; jj++) {
            acc[jj] += e0 * Wl[(k+0) * OUTd + jj];
            acc[jj] += e1 * Wl[(k+1) * OUTd + jj];
            acc[jj] += e2 * Wl[(k+2) * OUTd + jj];
            acc[jj] += e3 * Wl[(k+3) * OUTd + jj];
            acc[jj] += e4 * Wl[(k+4) * OUTd + jj];
            acc[jj] += e5 * Wl[(k+5) * OUTd + jj];
            acc[jj] += e6 * Wl[(k+6) * OUTd + jj];
            acc[jj] += e7 * Wl[(k+7) * OUTd + jj];
        }
    }
    #pragma unroll
    for (int jj = 0; jj < OUTd; jj++) out[(size_t)r * OUTd + jj] = acc[jj] + bl[jj];
}

extern "C" void kernel_launch(void* const* d_in, const int* in_sizes, int n_in,
                              void* d_out, int out_size, void* d_ws, size_t ws_size,
                              hipStream_t stream) {
    (void)in_sizes; (void)n_in; (void)out_size; (void)ws_size;

    const float* x   = (const float*)d_in[0];
    const float* W1  = (const float*)d_in[1];
    const float* b1  = (const float*)d_in[2];
    const float* W2  = (const float*)d_in[3];
    const float* b2  = (const float*)d_in[4];
    const float* g1  = (const float*)d_in[5];
    const float* bt1 = (const float*)d_in[6];
    const float* g2  = (const float*)d_in[7];
    const float* bt2 = (const float*)d_in[8];
    const float* Wc  = (const float*)d_in[9];
    const float* bc  = (const float*)d_in[10];
    const int*   ei  = (const int*)d_in[11];
    const int* srcp = ei;        // edge_index[0]
    const int* dstp = ei + Ee;   // edge_index[1]

    char* ws = (char*)d_ws;
    size_t off = 0;
    auto alloc = [&](size_t bytes) -> void* {
        void* p = ws + off;
        off += (bytes + 511) & ~(size_t)511;
        return p;
    };
    unsigned short* h   = (unsigned short*)alloc((size_t)Mm * 128 * 2);  // bf16 interleaved, dinv-scaled
    unsigned short* act = (unsigned short*)alloc((size_t)Mm * 128 * 2);  // bf16 interleaved
    float* dinv = (float*)alloc(Nn * 4);
    int*   cnt  = (int*)alloc(Nn * 4 + 2 * 256 * 4);  // cnt + S1 + S2 contiguous (one memset)
    float* S1   = (float*)(cnt + Nn);                 // sum[128], sumsq[128]
    float* S2   = S1 + 256;
    int*   ell  = (int*)alloc((size_t)Nn * ELLW * 4);

    float* out = (float*)d_out;

    // adjacency + stat-accumulator zeroing (1 memset + 2 kernels)
    hipMemsetAsync(cnt, 0, Nn * 4 + 2 * 256 * 4, stream);
    scatter_ell_k<<<(Ee + 255) / 256, 256, 0, stream>>>(srcp, dstp, cnt, ell);
    dinv_k<<<(Nn + 255) / 256, 256, 0, stream>>>(cnt, dinv);

    // Layer 1
    gemm1_k<<<Mm / 64, 256, 0, stream>>>(x, W1, dinv, h);
    agg_k<<<Nn / 4, 256, 0, stream>>>(h, ell, cnt, dinv, b1, act, S1);

    // Layer 2 (BN1 affine + d-init computed per-block inside gemm2)
    gemm2_k<<<Mm / 64, 256, 0, stream>>>(act, W2, g1, bt1, S1, dinv, h);
    agg_k<<<Nn / 4, 256, 0, stream>>>(h, ell, cnt, dinv, b2, act, S2);

    // Classifier (BN2 affine computed per-block)
    gemmout_k<<<(Mm + 255) / 256, 256, 0, stream>>>(act, Wc, bc, g2, bt2, S2, out);
}